// Round 1
// baseline (382.845 us; speedup 1.0000x reference)
//
#include <hip/hip_runtime.h>
#include <cstdint>
#include <cstddef>

typedef _Float16 f16;
typedef f16 f16x2 __attribute__((ext_vector_type(2)));
typedef f16 f16x4 __attribute__((ext_vector_type(4)));
typedef f16 f16x8 __attribute__((ext_vector_type(8)));
typedef float f32x4 __attribute__((ext_vector_type(4)));

#define NEXP 8
#define BM 128
#define BN 128
#define BK 32

// async global->LDS, 16B per lane. LDS dest must be wave-uniform base + lane*16
// (our staging index is tid*16 so this holds). Global source may be per-lane
// arbitrary (gathered rows are fine).
__device__ __forceinline__ void async_cp16(void* lds, const void* gsrc) {
  __builtin_amdgcn_global_load_lds(
      (const __attribute__((address_space(1))) void*)gsrc,
      (__attribute__((address_space(3))) void*)lds, 16, 0, 0);
}

// ---------------- K1: gating + x -> fp16 ----------------
// 256 threads = 4 waves, one token per wave.
__global__ __launch_bounds__(256) void k_gate(
    const float* __restrict__ x, const float* __restrict__ gw,
    f16* __restrict__ xb, int* __restrict__ gate, float* __restrict__ scale,
    int* __restrict__ cnt, float* __restrict__ probsum, int D)
{
  __shared__ float ps[NEXP];
  __shared__ int pc[NEXP];
  int tid = threadIdx.x, lane = tid & 63, w = tid >> 6;
  if (tid < NEXP) { ps[tid] = 0.f; pc[tid] = 0; }
  __syncthreads();

  int t = blockIdx.x * 4 + w;
  const float* xr = x + (size_t)t * D;
  f16* xbr = xb + (size_t)t * D;

  float acc[NEXP] = {};
  for (int d0 = lane * 4; d0 < D; d0 += 256) {
    float4 v = *(const float4*)(xr + d0);
    f16x4 h; h[0] = (f16)v.x; h[1] = (f16)v.y; h[2] = (f16)v.z; h[3] = (f16)v.w;
    *(f16x4*)(xbr + d0) = h;
    const float* g0 = gw + (size_t)d0 * NEXP;
    float xv[4] = {v.x, v.y, v.z, v.w};
#pragma unroll
    for (int j = 0; j < 4; j++) {
      float4 ga = *(const float4*)(g0 + j * NEXP);
      float4 gb = *(const float4*)(g0 + j * NEXP + 4);
      acc[0] += xv[j] * ga.x; acc[1] += xv[j] * ga.y;
      acc[2] += xv[j] * ga.z; acc[3] += xv[j] * ga.w;
      acc[4] += xv[j] * gb.x; acc[5] += xv[j] * gb.y;
      acc[6] += xv[j] * gb.z; acc[7] += xv[j] * gb.w;
    }
  }
#pragma unroll
  for (int e = 0; e < NEXP; e++) {
    float v = acc[e];
    for (int o = 32; o > 0; o >>= 1) v += __shfl_xor(v, o);
    acc[e] = v;
  }
  if (lane == 0) {
    float m = acc[0]; int g = 0;
#pragma unroll
    for (int e = 1; e < NEXP; e++) if (acc[e] > m) { m = acc[e]; g = e; }
    float pr[NEXP]; float ssum = 0.f;
#pragma unroll
    for (int e = 0; e < NEXP; e++) { pr[e] = expf(acc[e] - m); ssum += pr[e]; }
    float inv = 1.0f / ssum;
#pragma unroll
    for (int e = 0; e < NEXP; e++) atomicAdd(&ps[e], pr[e] * inv);
    atomicAdd(&pc[g], 1);
    gate[t] = g;
    scale[t] = pr[g] * inv;
  }
  __syncthreads();
  if (tid < NEXP) {
    atomicAdd(&probsum[tid], ps[tid]);
    atomicAdd(&cnt[tid], pc[tid]);
  }
}

// ---------------- K2: build Wfull^T in fp16 ----------------
// wt[e][n][d] = sum_p rule[e,p,a,b] * W[e,p,i,j], d = a*Dp+i, n = b*Op+j.
// n-major, d contiguous (K-contiguous for GEMM B staging).
__global__ __launch_bounds__(256) void k_wfull(
    const float* __restrict__ Wp, const float* __restrict__ rule,
    f16* __restrict__ wt, int Dp, int Op, int D, int O)
{
  int bid = blockIdx.x;
  int it = Dp >> 5, jt = Op >> 5;
  int itile = bid % it; bid /= it;
  int jtile = bid % jt; bid /= jt;
  int b = bid & 3; bid >>= 2;
  int e = bid;
  int i0 = itile * 32, j0 = jtile * 32;

  __shared__ float Wt[4][32][33];
  int tid = threadIdx.x;
  for (int idx = tid; idx < 4096; idx += 256) {
    int p = idx >> 10, rem = idx & 1023, ii = rem >> 5, jj = rem & 31;
    Wt[p][ii][jj] = Wp[(size_t)((e * 4 + p) * Dp + i0 + ii) * Op + j0 + jj];
  }
  float s[4][4];
#pragma unroll
  for (int p = 0; p < 4; p++)
#pragma unroll
    for (int a = 0; a < 4; a++)
      s[p][a] = rule[((e * 4 + p) * 4 + a) * 4 + b];
  __syncthreads();

  int ii = (tid & 15) * 2, jjb = tid >> 4;
#pragma unroll
  for (int a = 0; a < 4; a++) {
#pragma unroll
    for (int jp = 0; jp < 2; jp++) {
      int jj = jjb + jp * 16;
      float v0 = 0.f, v1 = 0.f;
#pragma unroll
      for (int p = 0; p < 4; p++) {
        v0 += s[p][a] * Wt[p][ii][jj];
        v1 += s[p][a] * Wt[p][ii + 1][jj];
      }
      size_t n = (size_t)b * Op + j0 + jj;
      size_t dd = (size_t)a * Dp + i0 + ii;
      f16x2 hv; hv[0] = (f16)v0; hv[1] = (f16)v1;
      *(f16x2*)(wt + ((size_t)e * O + n) * D + dd) = hv;
    }
  }
}

// ---------------- K3: plan (scan, loss, descriptors) ----------------
__global__ void k_plan(const int* __restrict__ cnt, const float* __restrict__ probsum,
                       int* __restrict__ offs, int* __restrict__ ndesc,
                       int2* __restrict__ desc, float* __restrict__ otail, int T)
{
  if (threadIdx.x != 0 || blockIdx.x != 0) return;
  int off = 0, nd = 0; float loss = 0.f;
  for (int e = 0; e < NEXP; e++) {
    offs[e] = off;
    int c = cnt[e];
    loss += probsum[e] * (float)c;
    for (int m0 = 0; m0 < c; m0 += BM) { desc[nd] = make_int2(e, m0); nd++; }
    off += c;
  }
  offs[NEXP] = off;
  *ndesc = nd;
  float invT = 1.0f / (float)T;
  otail[0] = (float)NEXP * loss * invT * invT;  // balance loss
  for (int e = 0; e < NEXP; e++) otail[1 + e] = (float)cnt[e];  // num_tokens
}

// ---------------- K4: scatter tokens by expert ----------------
__global__ __launch_bounds__(256) void k_scatter(
    const int* __restrict__ gate, const int* __restrict__ offs,
    int* __restrict__ cursor, int* __restrict__ perm)
{
  int t = blockIdx.x * 256 + threadIdx.x;
  int g = gate[t];
  int lane = threadIdx.x & 63;
  int pos = 0;
#pragma unroll
  for (int e = 0; e < NEXP; e++) {
    unsigned long long mask = __ballot(g == e);
    if (mask == 0ull) continue;            // wave-uniform
    int leader = __ffsll((unsigned long long)mask) - 1;
    int base = 0;
    if (lane == leader) base = atomicAdd(&cursor[e], (int)__popcll(mask));
    base = __shfl(base, leader);
    if (g == e) {
      int below = (int)__popcll(mask & ((1ull << lane) - 1ull));
      pos = offs[e] + base + below;
    }
  }
  perm[pos] = t;
}

// ---------------- K5: gathered top-1 GEMM, m97 structure ----------------
// 128x128 tile, BK=32, 4 waves in 2x2, each wave 4x4 of 16x16x32 f16 MFMA.
__global__ __launch_bounds__(256) void k_gemm(
    const f16* __restrict__ xb, const f16* __restrict__ wt,
    const float* __restrict__ bias, const int* __restrict__ perm,
    const int* __restrict__ cnt, const int* __restrict__ offs,
    const int* __restrict__ ndesc, const int2* __restrict__ desc,
    const float* __restrict__ scale, float* __restrict__ out, int D, int O)
{
  if ((int)blockIdx.x >= *ndesc) return;
  int2 dsc = desc[blockIdx.x];
  int e = dsc.x, m0 = dsc.y;
  int ce = cnt[e];
  int seg = offs[e];
  int n0 = blockIdx.y * BN;

  __shared__ f16 Al[BM * BK];
  __shared__ f16 Bl[BN * BK];
  __shared__ int tokS[BM];
  __shared__ float scS[BM];

  int tid = threadIdx.x;
  if (tid < BM) {
    int idx = m0 + tid; if (idx > ce - 1) idx = ce - 1;  // clamp partial tile
    int tok = perm[seg + idx];
    tokS[tid] = tok;
    scS[tid] = scale[tok];
  }
  __syncthreads();

  int r = tid >> 2;   // dest row 0..63
  int c = tid & 3;    // 16B chunk within 64B row
  const f16* a1 = xb + (size_t)tokS[r] * D + c * 8;
  const f16* a2 = xb + (size_t)tokS[r + 64] * D + c * 8;
  const f16* b1 = wt + ((size_t)e * O + n0 + r) * D + c * 8;
  const f16* b2 = wt + ((size_t)e * O + n0 + r + 64) * D + c * 8;
  f16* la1 = &Al[tid * 8];
  f16* la2 = &Al[2048 + tid * 8];
  f16* lb1 = &Bl[tid * 8];
  f16* lb2 = &Bl[2048 + tid * 8];

  int lane = tid & 63;
  int w = tid >> 6;
  int wm = (w & 1) * 64, wn = (w >> 1) * 64;
  int lr = lane & 15, q = lane >> 4;

  f32x4 acc[4][4] = {};

  int nk = D / BK;
  for (int kk = 0; kk < nk; ++kk) {
    async_cp16(la1, a1 + kk * BK);
    async_cp16(la2, a2 + kk * BK);
    async_cp16(lb1, b1 + kk * BK);
    async_cp16(lb2, b2 + kk * BK);
    __syncthreads();  // compiler emits vmcnt(0) drain before s_barrier
    f16x8 af[4], bf[4];
#pragma unroll
    for (int mi = 0; mi < 4; mi++)
      af[mi] = *(const f16x8*)&Al[(wm + mi * 16 + lr) * BK + q * 8];
#pragma unroll
    for (int ni = 0; ni < 4; ni++)
      bf[ni] = *(const f16x8*)&Bl[(wn + ni * 16 + lr) * BK + q * 8];
#pragma unroll
    for (int mi = 0; mi < 4; mi++)
#pragma unroll
      for (int ni = 0; ni < 4; ni++)
        acc[mi][ni] = __builtin_amdgcn_mfma_f32_16x16x32_f16(
            af[mi], bf[ni], acc[mi][ni], 0, 0, 0);
    __syncthreads();
  }

  // epilogue: C/D layout col=lane&15, row=(lane>>4)*4+reg
  float bv[4];
#pragma unroll
  for (int ni = 0; ni < 4; ni++)
    bv[ni] = bias[(size_t)e * O + n0 + wn + ni * 16 + lr];
#pragma unroll
  for (int mi = 0; mi < 4; mi++) {
#pragma unroll
    for (int rg = 0; rg < 4; rg++) {
      int rl = wm + mi * 16 + q * 4 + rg;
      if (m0 + rl < ce) {
        float s = scS[rl];
        float* orow = out + (size_t)tokS[rl] * O + n0 + wn;
#pragma unroll
        for (int ni = 0; ni < 4; ni++)
          orow[ni * 16 + lr] = (acc[mi][ni][rg] + bv[ni]) * s;
      }
    }
  }
}

extern "C" void kernel_launch(void* const* d_in, const int* in_sizes, int n_in,
                              void* d_out, int out_size, void* d_ws, size_t ws_size,
                              hipStream_t stream)
{
  const float* x    = (const float*)d_in[0];   // [T, D]
  const float* gw   = (const float*)d_in[1];   // [D, 8]
  const float* rule = (const float*)d_in[2];   // [8, 4, 4, 4]
  const float* W    = (const float*)d_in[3];   // [8, 4, D/4, O/4]
  const float* bias = (const float*)d_in[4];   // [8, O]
  float* out = (float*)d_out;

  int D = in_sizes[1] / NEXP;
  int O = in_sizes[4] / NEXP;
  int T = in_sizes[0] / D;
  int Dp = D / 4, Op = O / 4;

  uint8_t* ws = (uint8_t*)d_ws;
  size_t off = 0;
  f16* xb = (f16*)(ws + off);  off += (size_t)T * D * 2;
  f16* wt = (f16*)(ws + off);  off += (size_t)NEXP * O * D * 2;
  int*   gate  = (int*)(ws + off);   off += (size_t)T * 4;
  float* scale = (float*)(ws + off); off += (size_t)T * 4;
  int*   perm  = (int*)(ws + off);   off += (size_t)T * 4;
  off = (off + 255) & ~(size_t)255;
  uint8_t* C = ws + off;
  int*   cnt     = (int*)(C + 0);
  float* probsum = (float*)(C + 32);
  int*   cursor  = (int*)(C + 64);
  int*   ndesc   = (int*)(C + 96);
  int*   offs    = (int*)(C + 128);
  int2*  desc    = (int2*)(C + 192);   // capacity 128 entries

  // zero cnt/probsum/cursor/ndesc (ws is re-poisoned 0xAA before every call)
  hipMemsetAsync(C, 0, 128, stream);

  k_gate<<<T / 4, 256, 0, stream>>>(x, gw, xb, gate, scale, cnt, probsum, D);
  k_wfull<<<NEXP * 4 * (Op / 32) * (Dp / 32), 256, 0, stream>>>(W, rule, wt, Dp, Op, D, O);
  k_plan<<<1, 1, 0, stream>>>(cnt, probsum, offs, ndesc, desc, out + (size_t)T * O, T);
  k_scatter<<<T / 256, 256, 0, stream>>>(gate, offs, cursor, perm);

  int maxdesc = T / BM + NEXP;  // worst-case row-block descriptor count
  k_gemm<<<dim3(maxdesc, O / BN), 256, 0, stream>>>(
      xb, wt, bias, perm, cnt, offs, ndesc, desc, scale, out, D, O);
}